// Round 2
// baseline (453.057 us; speedup 1.0000x reference)
//
#include <hip/hip_runtime.h>

#define NN 50000
#define NE 800000
#define DD 128
#define ED 32

__device__ __forceinline__ float4 ld4(const float* p) {
    return *reinterpret_cast<const float4*>(p);
}
__device__ __forceinline__ void fma4(float4& a, float s, float4 w) {
    a.x = fmaf(s, w.x, a.x);
    a.y = fmaf(s, w.y, a.y);
    a.z = fmaf(s, w.z, a.z);
    a.w = fmaf(s, w.w, a.w);
}
__device__ __forceinline__ float bcast(float v, int srclane) {
    return __uint_as_float(__builtin_amdgcn_readlane(__float_as_uint(v), srclane));
}

// ---------------------------------------------------------------- edge stage
// Wave processes 2 edges/iter. Edge rows arrive via ONE coalesced vector load
// (lanes 0-31 = edge A row, lanes 32-63 = edge B row) and are broadcast with
// v_readlane -> pure VALU, no SMEM latency chain. Software pipeline:
// indices 2-deep, rows + x-gathers 1-deep.
__global__ __launch_bounds__(256, 4)
void k_edge(const float* __restrict__ x, const int* __restrict__ ei,
            const float* __restrict__ ea, const float* __restrict__ We,
            const float* __restrict__ be, float* __restrict__ agg)
{
    const int lane = threadIdx.x & 63;
    const int wid  = (blockIdx.x << 2) | (threadIdx.x >> 6);
    const int nw   = gridDim.x << 2;

    float w0[ED], w1[ED];
#pragma unroll
    for (int k = 0; k < ED; ++k) {
        w0[k] = We[k * DD + lane];
        w1[k] = We[k * DD + 64 + lane];
    }
    const float b0 = be[lane], b1 = be[64 + lane];

    // int64-vs-int32 sniff: int64 indices < 2^32 have zero high words.
    const int is64 = ((ei[1] | ei[3] | ei[5] | ei[7]) == 0) ? 1 : 0;

    const int NP = NE / 2;
    const int chunk = (NP + nw - 1) / nw;
    const int pb = wid * chunk;
    const int pe = min(pb + chunk, NP);
    if (pb >= pe) return;

    // ---- prologue: indices for pair pb
    const long e0 = (long)pb * 2;
    int sA = ei[e0 << is64];
    int sB = ei[(e0 + 1) << is64];
    int dA = ei[(NE + e0) << is64];
    int dB = ei[(NE + e0 + 1) << is64];
    // row + x gathers for pair pb
    float r   = ea[(e0 + (lane >> 5)) * ED + (lane & 31)];
    float xA0 = x[(size_t)sA * DD + lane], xA1 = x[(size_t)sA * DD + 64 + lane];
    float xB0 = x[(size_t)sB * DD + lane], xB1 = x[(size_t)sB * DD + 64 + lane];
    // indices for pair pb+1
    {
        const long e1 = (long)min(pb + 1, pe - 1) * 2;
        const int t0 = ei[e1 << is64];
        const int t1 = ei[(e1 + 1) << is64];
        const int t2 = ei[(NE + e1) << is64];
        const int t3 = ei[(NE + e1 + 1) << is64];
        // stash "next" index set
        sA = sA; sB = sB; // keep current in sA/sB; next in below vars
        // use separate regs:
        // (assigned after current consumed in loop)
        // store into pipeline vars:
        // handled via variables declared next
        // (actual assignment below)
        // -- we fold this into named vars:
        // nxt idx:
        // note: kept simple; compiler renames registers
        // (code continues)
        // store:
        // (see loop state)
        // ---
        // assign:
        // next-index registers:
        // (declared here)
        // done
        // --- real assignments:
        // (see below)
        (void)t0; (void)t1; (void)t2; (void)t3;
        // re-declare properly:
        // (fallthrough)
        // NOTE: replaced by structured code below
        // --- structured:
        // next index regs
        // (cannot re-declare inside braces; so:)
        // moved outside
        goto after_stub;
    after_stub:;
        // assign next-index registers (declared below before loop)
        // (handled right after this block)
        // --- we simply re-load below; cheap scalar ops
        // (kept to preserve pipeline structure)
        // fallthrough
        // (end)
        // --- actually assign:
        // see nsA/nsB/ndA/ndB init below
        ;
    }
    // next-pair index registers (2-deep pipeline)
    long e1 = (long)min(pb + 1, pe - 1) * 2;
    int nsA = ei[e1 << is64];
    int nsB = ei[(e1 + 1) << is64];
    int ndA = ei[(NE + e1) << is64];
    int ndB = ei[(NE + e1 + 1) << is64];

    for (int p = pb; p < pe; ++p) {
        // snapshot current pair's operands
        const float rc = r;
        const int   dAc = dA, dBc = dB;
        const float xA0c = xA0, xA1c = xA1, xB0c = xB0, xB1c = xB1;

        // advance index pipeline: "next" becomes current-for-prefetch
        const int sAp = nsA, sBp = nsB;
        dA = ndA; dB = ndB;

        // issue index loads for p+2
        const long e2 = (long)min(p + 2, pe - 1) * 2;
        nsA = ei[e2 << is64];
        nsB = ei[(e2 + 1) << is64];
        ndA = ei[(NE + e2) << is64];
        ndB = ei[(NE + e2 + 1) << is64];

        // issue row + x-gather loads for p+1 (indices loaded one iter ago)
        const long en = (long)min(p + 1, pe - 1) * 2;
        r   = ea[(en + (lane >> 5)) * ED + (lane & 31)];
        xA0 = x[(size_t)sAp * DD + lane]; xA1 = x[(size_t)sAp * DD + 64 + lane];
        xB0 = x[(size_t)sBp * DD + lane]; xB1 = x[(size_t)sBp * DD + 64 + lane];

        // compute current pair: broadcast row values via readlane
        float aA0 = b0, aA1 = b1, aB0 = b0, aB1 = b1;
#pragma unroll
        for (int k = 0; k < ED; ++k) {
            const float vA = bcast(rc, k);
            const float vB = bcast(rc, 32 + k);
            aA0 = fmaf(vA, w0[k], aA0);
            aA1 = fmaf(vA, w1[k], aA1);
            aB0 = fmaf(vB, w0[k], aB0);
            aB1 = fmaf(vB, w1[k], aB1);
        }
        float* arA = agg + (size_t)dAc * DD;
        float* arB = agg + (size_t)dBc * DD;
        unsafeAtomicAdd(arA + lane,      fmaxf(xA0c + aA0, 0.0f));
        unsafeAtomicAdd(arA + lane + 64, fmaxf(xA1c + aA1, 0.0f));
        unsafeAtomicAdd(arB + lane,      fmaxf(xB0c + aB0, 0.0f));
        unsafeAtomicAdd(arB + lane + 64, fmaxf(xB1c + aB1, 0.0f));
    }
}

// ---------------------------------------------------------------- conv stage
// conv = (x + agg) @ Wc + bc.  Wc in LDS (64KB).  Half-wave computes 4 nodes,
// each lane owns a d-quad (d = 4q..4q+3, q = lane&31).
__global__ __launch_bounds__(256, 2)
void k_conv(const float* __restrict__ x, const float* __restrict__ agg,
            const float* __restrict__ Wc, const float* __restrict__ bc,
            float* __restrict__ conv)
{
    __shared__ float sW[DD * DD];
    for (int i = threadIdx.x * 4; i < DD * DD; i += 1024)
        *reinterpret_cast<float4*>(&sW[i]) = ld4(&Wc[i]);
    __syncthreads();

    const int lane = threadIdx.x & 63;
    const int q    = lane & 31;
    const int wib  = threadIdx.x >> 6;
    const int half = lane >> 5;

    const float4 bcv = ld4(&bc[q * 4]);
    const int ntiles = (NN + 31) / 32;

    for (int tile = blockIdx.x; tile < ntiles; tile += gridDim.x) {
        const int base = tile * 32 + wib * 8 + half * 4;
        const int n0 = min(base + 0, NN - 1);
        const int n1 = min(base + 1, NN - 1);
        const int n2 = min(base + 2, NN - 1);
        const int n3 = min(base + 3, NN - 1);
        const float* x0 = x + (size_t)n0 * DD; const float* g0 = agg + (size_t)n0 * DD;
        const float* x1 = x + (size_t)n1 * DD; const float* g1 = agg + (size_t)n1 * DD;
        const float* x2 = x + (size_t)n2 * DD; const float* g2 = agg + (size_t)n2 * DD;
        const float* x3 = x + (size_t)n3 * DD; const float* g3 = agg + (size_t)n3 * DD;
        float4 acc0 = bcv, acc1 = bcv, acc2 = bcv, acc3 = bcv;
#pragma unroll 2
        for (int j = 0; j < DD; j += 4) {
            const float4 wv0 = ld4(&sW[(j + 0) * DD + q * 4]);
            const float4 wv1 = ld4(&sW[(j + 1) * DD + q * 4]);
            const float4 wv2 = ld4(&sW[(j + 2) * DD + q * 4]);
            const float4 wv3 = ld4(&sW[(j + 3) * DD + q * 4]);
            float4 xa, ga;
            xa = ld4(x0 + j); ga = ld4(g0 + j);
            fma4(acc0, xa.x + ga.x, wv0); fma4(acc0, xa.y + ga.y, wv1);
            fma4(acc0, xa.z + ga.z, wv2); fma4(acc0, xa.w + ga.w, wv3);
            xa = ld4(x1 + j); ga = ld4(g1 + j);
            fma4(acc1, xa.x + ga.x, wv0); fma4(acc1, xa.y + ga.y, wv1);
            fma4(acc1, xa.z + ga.z, wv2); fma4(acc1, xa.w + ga.w, wv3);
            xa = ld4(x2 + j); ga = ld4(g2 + j);
            fma4(acc2, xa.x + ga.x, wv0); fma4(acc2, xa.y + ga.y, wv1);
            fma4(acc2, xa.z + ga.z, wv2); fma4(acc2, xa.w + ga.w, wv3);
            xa = ld4(x3 + j); ga = ld4(g3 + j);
            fma4(acc3, xa.x + ga.x, wv0); fma4(acc3, xa.y + ga.y, wv1);
            fma4(acc3, xa.z + ga.z, wv2); fma4(acc3, xa.w + ga.w, wv3);
        }
        if (base + 0 < NN) *reinterpret_cast<float4*>(&conv[(size_t)n0 * DD + q * 4]) = acc0;
        if (base + 1 < NN) *reinterpret_cast<float4*>(&conv[(size_t)n1 * DD + q * 4]) = acc1;
        if (base + 2 < NN) *reinterpret_cast<float4*>(&conv[(size_t)n2 * DD + q * 4]) = acc2;
        if (base + 3 < NN) *reinterpret_cast<float4*>(&conv[(size_t)n3 * DD + q * 4]) = acc3;
    }
}

// ---------------------------------------------------------------- gate stage
// gate = sigmoid(conv @ Wg[0:128] + imp*Wg[128] + bg); out = x + g*(conv-x);
// prop = out @ Wp + bp.  conv is read from d_out and overwritten in place.
__global__ __launch_bounds__(256, 2)
void k_gate(const float* __restrict__ x, const float* conv,
            const float* __restrict__ imp, const float* __restrict__ Wg,
            const float* __restrict__ bg, const float* __restrict__ Wp,
            const float* __restrict__ bp, float* outp, float* __restrict__ prop)
{
    __shared__ float sW[DD * DD];
    for (int i = threadIdx.x * 4; i < DD * DD; i += 1024)
        *reinterpret_cast<float4*>(&sW[i]) = ld4(&Wg[i]);   // rows 0..127
    __syncthreads();

    const int lane = threadIdx.x & 63;
    const int q    = lane & 31;
    const int wib  = threadIdx.x >> 6;
    const int half = lane >> 5;

    const float4 bgv = ld4(&bg[q * 4]);
    const float4 wgi = ld4(&Wg[DD * DD + q * 4]);   // importance row (row 128)
    const float4 wp4 = ld4(&Wp[q * 4]);
    const float  bps = bp[0];
    const int ntiles = (NN + 31) / 32;

    for (int tile = blockIdx.x; tile < ntiles; tile += gridDim.x) {
        const int base = tile * 32 + wib * 8 + half * 4;
        const int n0 = min(base + 0, NN - 1);
        const int n1 = min(base + 1, NN - 1);
        const int n2 = min(base + 2, NN - 1);
        const int n3 = min(base + 3, NN - 1);
        const float* c0 = conv + (size_t)n0 * DD;
        const float* c1 = conv + (size_t)n1 * DD;
        const float* c2 = conv + (size_t)n2 * DD;
        const float* c3 = conv + (size_t)n3 * DD;
        float4 acc0 = bgv, acc1 = bgv, acc2 = bgv, acc3 = bgv;
#pragma unroll 2
        for (int j = 0; j < DD; j += 4) {
            const float4 wv0 = ld4(&sW[(j + 0) * DD + q * 4]);
            const float4 wv1 = ld4(&sW[(j + 1) * DD + q * 4]);
            const float4 wv2 = ld4(&sW[(j + 2) * DD + q * 4]);
            const float4 wv3 = ld4(&sW[(j + 3) * DD + q * 4]);
            float4 cv;
            cv = ld4(c0 + j);
            fma4(acc0, cv.x, wv0); fma4(acc0, cv.y, wv1);
            fma4(acc0, cv.z, wv2); fma4(acc0, cv.w, wv3);
            cv = ld4(c1 + j);
            fma4(acc1, cv.x, wv0); fma4(acc1, cv.y, wv1);
            fma4(acc1, cv.z, wv2); fma4(acc1, cv.w, wv3);
            cv = ld4(c2 + j);
            fma4(acc2, cv.x, wv0); fma4(acc2, cv.y, wv1);
            fma4(acc2, cv.z, wv2); fma4(acc2, cv.w, wv3);
            cv = ld4(c3 + j);
            fma4(acc3, cv.x, wv0); fma4(acc3, cv.y, wv1);
            fma4(acc3, cv.z, wv2); fma4(acc3, cv.w, wv3);
        }

        float s[4];
        const int   ns[4] = {n0, n1, n2, n3};
        float4      as[4] = {acc0, acc1, acc2, acc3};
#pragma unroll
        for (int m = 0; m < 4; ++m) {
            const int n = ns[m];
            float4 a = as[m];
            fma4(a, imp[n], wgi);
            float4 g;
            g.x = 1.0f / (1.0f + expf(-a.x));
            g.y = 1.0f / (1.0f + expf(-a.y));
            g.z = 1.0f / (1.0f + expf(-a.z));
            g.w = 1.0f / (1.0f + expf(-a.w));
            const float4 cv = ld4(&conv[(size_t)n * DD + q * 4]);
            const float4 xv = ld4(&x[(size_t)n * DD + q * 4]);
            float4 o;
            o.x = fmaf(g.x, cv.x - xv.x, xv.x);
            o.y = fmaf(g.y, cv.y - xv.y, xv.y);
            o.z = fmaf(g.z, cv.z - xv.z, xv.z);
            o.w = fmaf(g.w, cv.w - xv.w, xv.w);
            if (base + m < NN)
                *reinterpret_cast<float4*>(&outp[(size_t)n * DD + q * 4]) = o;
            s[m] = o.x * wp4.x + o.y * wp4.y + o.z * wp4.z + o.w * wp4.w;
        }
#pragma unroll
        for (int off = 16; off; off >>= 1) {
            s[0] += __shfl_xor(s[0], off);
            s[1] += __shfl_xor(s[1], off);
            s[2] += __shfl_xor(s[2], off);
            s[3] += __shfl_xor(s[3], off);
        }
        if (q == 0) {
#pragma unroll
            for (int m = 0; m < 4; ++m)
                if (base + m < NN) prop[base + m] = s[m] + bps;
        }
    }
}

extern "C" void kernel_launch(void* const* d_in, const int* in_sizes, int n_in,
                              void* d_out, int out_size, void* d_ws, size_t ws_size,
                              hipStream_t stream) {
    const float* x   = (const float*)d_in[0];
    const int*   ei  = (const int*)d_in[1];
    const float* ea  = (const float*)d_in[2];
    const float* imp = (const float*)d_in[3];
    const float* We  = (const float*)d_in[4];
    const float* be  = (const float*)d_in[5];
    const float* Wc  = (const float*)d_in[6];
    const float* bc  = (const float*)d_in[7];
    const float* Wg  = (const float*)d_in[8];
    const float* bg  = (const float*)d_in[9];
    const float* Wp  = (const float*)d_in[10];
    const float* bp  = (const float*)d_in[11];

    float* out  = (float*)d_out;                 // [NN, DD]
    float* prop = out + (size_t)NN * DD;         // [NN]
    float* agg  = (float*)d_ws;                  // [NN, DD] scratch

    hipMemsetAsync(agg, 0, (size_t)NN * DD * sizeof(float), stream);
    hipLaunchKernelGGL(k_edge, dim3(4096), dim3(256), 0, stream, x, ei, ea, We, be, agg);
    hipLaunchKernelGGL(k_conv, dim3(512), dim3(256), 0, stream, x, agg, Wc, bc, out);
    hipLaunchKernelGGL(k_gate, dim3(512), dim3(256), 0, stream,
                       x, out, imp, Wg, bg, Wp, bp, out, prop);
}

// Round 3
// 405.246 us; speedup vs baseline: 1.1180x; 1.1180x over previous
//
#include <hip/hip_runtime.h>

#define NN 50000
#define NE 800000
#define DD 128
#define ED 32

__device__ __forceinline__ float4 ld4(const float* p) {
    return *reinterpret_cast<const float4*>(p);
}
__device__ __forceinline__ void fma4(float4& a, float s, float4 w) {
    a.x = fmaf(s, w.x, a.x);
    a.y = fmaf(s, w.y, a.y);
    a.z = fmaf(s, w.z, a.z);
    a.w = fmaf(s, w.w, a.w);
}
__device__ __forceinline__ float bcast(float v, int l) {
    return __uint_as_float(__builtin_amdgcn_readlane(__float_as_uint(v), l));
}
__device__ __forceinline__ int rli(int v, int l) {
    return __builtin_amdgcn_readlane(v, l);
}
__device__ __forceinline__ int sniff64(const int* ei) {
    // int64 indices < 2^32: every odd 32-bit word is zero.
    return ((ei[1] | ei[3] | ei[5] | ei[7]) == 0) ? 1 : 0;
}

// ============================================================ CSR build
__global__ __launch_bounds__(256)
void k_hist(const int* __restrict__ ei, int* __restrict__ counts) {
    const int is64 = sniff64(ei);
    for (int e = blockIdx.x * blockDim.x + threadIdx.x; e < NE;
         e += gridDim.x * blockDim.x) {
        const int dst = ei[(NE + e) << is64];
        atomicAdd(&counts[dst], 1);
    }
}

__global__ __launch_bounds__(1024)
void k_scan(const int* __restrict__ counts, int* __restrict__ rowptr,
            int* __restrict__ cursor)
{
    __shared__ int wsum[16];
    __shared__ int wexcl[16];
    __shared__ int s_run, s_tot;
    const int tid  = threadIdx.x;
    const int lane = tid & 63;
    const int w    = tid >> 6;
    if (tid == 0) s_run = 0;
    __syncthreads();
    int c = (tid < NN) ? counts[tid] : 0;
    for (int base = 0; base < NN; base += 1024) {
        const int inext = base + 1024 + tid;
        const int cn = (inext < NN) ? counts[inext] : 0;   // prefetch next chunk
        int s = c;
#pragma unroll
        for (int off = 1; off < 64; off <<= 1) {
            const int t = __shfl_up(s, off, 64);
            if (lane >= off) s += t;
        }
        if (lane == 63) wsum[w] = s;
        __syncthreads();
        if (w == 0) {
            int vv = wsum[lane & 15];
            const int orig = vv;
#pragma unroll
            for (int off = 1; off < 16; off <<= 1) {
                const int t = __shfl_up(vv, off, 16);
                if ((lane & 15) >= off) vv += t;
            }
            if (lane < 16)  wexcl[lane] = vv - orig;
            if (lane == 15) s_tot = vv;
        }
        __syncthreads();
        const int idx  = base + tid;
        const int excl = s_run + wexcl[w] + s - c;
        if (idx < NN) { rowptr[idx] = excl; cursor[idx] = excl; }
        __syncthreads();
        if (tid == 0) s_run += s_tot;
        c = cn;
        __syncthreads();
    }
    if (tid == 0) rowptr[NN] = s_run;
}

__global__ __launch_bounds__(256)
void k_scatter(const int* __restrict__ ei, int* __restrict__ cursor,
               int2* __restrict__ sdat) {
    const int is64 = sniff64(ei);
    for (int e = blockIdx.x * blockDim.x + threadIdx.x; e < NE;
         e += gridDim.x * blockDim.x) {
        const int src = ei[(long)e << is64];
        const int dst = ei[(long)(NE + e) << is64];
        const int pos = atomicAdd(&cursor[dst], 1);
        sdat[pos] = make_int2(src, e);
    }
}

// ============================================================ aggregation
// One wave per node (grid-stride). Adjacency descriptors fetched in one
// coalesced int2 load per 64 edges, broadcast via v_readlane. Edge-lin
// matvec: We columns (lane, lane+64) resident in 64 VGPRs, ea row arrives
// as a coalesced vector load (lanes 0-31 edge A, 32-63 edge B) and is
// broadcast with readlane. Writes pre = x[n] + agg[n] (no atomics).
__global__ __launch_bounds__(256, 4)
void k_agg(const float* __restrict__ x, const float* __restrict__ ea,
           const float* __restrict__ We, const float* __restrict__ be,
           const int* __restrict__ rowptr, const int2* __restrict__ sdat,
           float* __restrict__ pre)
{
    const int lane = threadIdx.x & 63;
    const int wid  = (blockIdx.x << 2) | (threadIdx.x >> 6);
    const int nw   = gridDim.x << 2;

    float w0[ED], w1[ED];
#pragma unroll
    for (int k = 0; k < ED; ++k) {
        w0[k] = We[k * DD + lane];
        w1[k] = We[k * DD + 64 + lane];
    }
    const float b0 = be[lane], b1 = be[64 + lane];

    for (int n = wid; n < NN; n += nw) {
        const int beg = rowptr[n], end = rowptr[n + 1];
        float a0 = 0.0f, a1 = 0.0f;

        for (int cb = beg; cb < end; cb += 64) {
            const int m = min(64, end - cb);
            int2 dv = make_int2(0, 0);
            if (lane < m) dv = sdat[cb + lane];

            // prologue: loads for pair 0
            int sA = rli(dv.x, 0);
            int iA = rli(dv.y, 0);
            int sB = (m > 1) ? rli(dv.x, 1) : sA;
            int iB = (m > 1) ? rli(dv.y, 1) : iA;
            float r   = ea[(size_t)((lane < 32) ? iA : iB) * ED + (lane & 31)];
            float xa0 = x[(size_t)sA * DD + lane];
            float xa1 = x[(size_t)sA * DD + 64 + lane];
            float xb0 = x[(size_t)sB * DD + lane];
            float xb1 = x[(size_t)sB * DD + 64 + lane];

            for (int j = 0; j < m; j += 2) {
                const float rc = r;
                const float ya0 = xa0, ya1 = xa1, yb0 = xb0, yb1 = xb1;
                const bool hasB = (j + 1 < m);

                // prefetch pair j+2 (indices already in dv registers)
                if (j + 2 < m) {
                    const int nA = rli(dv.x, j + 2);
                    const int kA = rli(dv.y, j + 2);
                    const int nB = (j + 3 < m) ? rli(dv.x, j + 3) : nA;
                    const int kB = (j + 3 < m) ? rli(dv.y, j + 3) : kA;
                    r   = ea[(size_t)((lane < 32) ? kA : kB) * ED + (lane & 31)];
                    xa0 = x[(size_t)nA * DD + lane];
                    xa1 = x[(size_t)nA * DD + 64 + lane];
                    xb0 = x[(size_t)nB * DD + lane];
                    xb1 = x[(size_t)nB * DD + 64 + lane];
                }

                float eA0 = b0, eA1 = b1, eB0 = b0, eB1 = b1;
#pragma unroll
                for (int k = 0; k < ED; ++k) {
                    const float vA = bcast(rc, k);
                    const float vB = bcast(rc, 32 + k);
                    eA0 = fmaf(vA, w0[k], eA0);
                    eA1 = fmaf(vA, w1[k], eA1);
                    eB0 = fmaf(vB, w0[k], eB0);
                    eB1 = fmaf(vB, w1[k], eB1);
                }
                a0 += fmaxf(ya0 + eA0, 0.0f);
                a1 += fmaxf(ya1 + eA1, 0.0f);
                if (hasB) {                 // wave-uniform branch
                    a0 += fmaxf(yb0 + eB0, 0.0f);
                    a1 += fmaxf(yb1 + eB1, 0.0f);
                }
            }
        }
        // pre = x[n] + agg
        pre[(size_t)n * DD + lane]      = a0 + x[(size_t)n * DD + lane];
        pre[(size_t)n * DD + 64 + lane] = a1 + x[(size_t)n * DD + 64 + lane];
    }
}

// ============================================================ fallback edge
__global__ __launch_bounds__(256, 4)
void k_edge_atomic(const float* __restrict__ x, const int* __restrict__ ei,
                   const float* __restrict__ ea, const float* __restrict__ We,
                   const float* __restrict__ be, float* __restrict__ agg)
{
    const int lane = threadIdx.x & 63;
    const int wid  = (blockIdx.x << 2) | (threadIdx.x >> 6);
    const int nw   = gridDim.x << 2;

    float w0[ED], w1[ED];
#pragma unroll
    for (int k = 0; k < ED; ++k) {
        w0[k] = We[k * DD + lane];
        w1[k] = We[k * DD + 64 + lane];
    }
    const float b0 = be[lane], b1 = be[64 + lane];
    const int is64 = sniff64(ei);

    const int chunk = (NE + nw - 1) / nw;
    const int eBeg = wid * chunk;
    const int eEnd = min(eBeg + chunk, NE);
    for (int e = eBeg; e < eEnd; ++e) {
        const int es  = __builtin_amdgcn_readfirstlane(e);
        const int src = ei[(long)es << is64];
        const int dst = ei[(long)(NE + es) << is64];
        const float* eap = ea + (size_t)es * ED;
        float a0 = b0, a1 = b1;
#pragma unroll
        for (int k = 0; k < ED; ++k) {
            const float v = eap[k];
            a0 = fmaf(v, w0[k], a0);
            a1 = fmaf(v, w1[k], a1);
        }
        const float* xr = x + (size_t)src * DD;
        float* ar = agg + (size_t)dst * DD;
        unsafeAtomicAdd(ar + lane,      fmaxf(xr[lane] + a0, 0.0f));
        unsafeAtomicAdd(ar + lane + 64, fmaxf(xr[lane + 64] + a1, 0.0f));
    }
}

__global__ __launch_bounds__(256)
void k_addx(const float* __restrict__ x, float* __restrict__ agg) {
    const int n4 = NN * DD / 4;
    for (int i = blockIdx.x * blockDim.x + threadIdx.x; i < n4;
         i += gridDim.x * blockDim.x) {
        float4 a = reinterpret_cast<float4*>(agg)[i];
        const float4 xv = reinterpret_cast<const float4*>(x)[i];
        a.x += xv.x; a.y += xv.y; a.z += xv.z; a.w += xv.w;
        reinterpret_cast<float4*>(agg)[i] = a;
    }
}

// ============================================================ conv stage
// conv = pre @ Wc + bc.  Wc in LDS (64KB).  Half-wave computes 4 nodes,
// each lane owns a d-quad (d = 4q..4q+3, q = lane&31).
__global__ __launch_bounds__(256, 2)
void k_conv(const float* __restrict__ pre, const float* __restrict__ Wc,
            const float* __restrict__ bc, float* __restrict__ conv)
{
    __shared__ float sW[DD * DD];
    for (int i = threadIdx.x * 4; i < DD * DD; i += 1024)
        *reinterpret_cast<float4*>(&sW[i]) = ld4(&Wc[i]);
    __syncthreads();

    const int lane = threadIdx.x & 63;
    const int q    = lane & 31;
    const int wib  = threadIdx.x >> 6;
    const int half = lane >> 5;

    const float4 bcv = ld4(&bc[q * 4]);
    const int ntiles = (NN + 31) / 32;

    for (int tile = blockIdx.x; tile < ntiles; tile += gridDim.x) {
        const int base = tile * 32 + wib * 8 + half * 4;
        const int n0 = min(base + 0, NN - 1);
        const int n1 = min(base + 1, NN - 1);
        const int n2 = min(base + 2, NN - 1);
        const int n3 = min(base + 3, NN - 1);
        const float* p0 = pre + (size_t)n0 * DD;
        const float* p1 = pre + (size_t)n1 * DD;
        const float* p2 = pre + (size_t)n2 * DD;
        const float* p3 = pre + (size_t)n3 * DD;
        float4 acc0 = bcv, acc1 = bcv, acc2 = bcv, acc3 = bcv;
#pragma unroll 2
        for (int j = 0; j < DD; j += 4) {
            const float4 wv0 = ld4(&sW[(j + 0) * DD + q * 4]);
            const float4 wv1 = ld4(&sW[(j + 1) * DD + q * 4]);
            const float4 wv2 = ld4(&sW[(j + 2) * DD + q * 4]);
            const float4 wv3 = ld4(&sW[(j + 3) * DD + q * 4]);
            float4 v;
            v = ld4(p0 + j);
            fma4(acc0, v.x, wv0); fma4(acc0, v.y, wv1);
            fma4(acc0, v.z, wv2); fma4(acc0, v.w, wv3);
            v = ld4(p1 + j);
            fma4(acc1, v.x, wv0); fma4(acc1, v.y, wv1);
            fma4(acc1, v.z, wv2); fma4(acc1, v.w, wv3);
            v = ld4(p2 + j);
            fma4(acc2, v.x, wv0); fma4(acc2, v.y, wv1);
            fma4(acc2, v.z, wv2); fma4(acc2, v.w, wv3);
            v = ld4(p3 + j);
            fma4(acc3, v.x, wv0); fma4(acc3, v.y, wv1);
            fma4(acc3, v.z, wv2); fma4(acc3, v.w, wv3);
        }
        if (base + 0 < NN) *reinterpret_cast<float4*>(&conv[(size_t)n0 * DD + q * 4]) = acc0;
        if (base + 1 < NN) *reinterpret_cast<float4*>(&conv[(size_t)n1 * DD + q * 4]) = acc1;
        if (base + 2 < NN) *reinterpret_cast<float4*>(&conv[(size_t)n2 * DD + q * 4]) = acc2;
        if (base + 3 < NN) *reinterpret_cast<float4*>(&conv[(size_t)n3 * DD + q * 4]) = acc3;
    }
}

// ============================================================ gate stage
__global__ __launch_bounds__(256, 2)
void k_gate(const float* __restrict__ x, const float* conv,
            const float* __restrict__ imp, const float* __restrict__ Wg,
            const float* __restrict__ bg, const float* __restrict__ Wp,
            const float* __restrict__ bp, float* outp, float* __restrict__ prop)
{
    __shared__ float sW[DD * DD];
    for (int i = threadIdx.x * 4; i < DD * DD; i += 1024)
        *reinterpret_cast<float4*>(&sW[i]) = ld4(&Wg[i]);   // rows 0..127
    __syncthreads();

    const int lane = threadIdx.x & 63;
    const int q    = lane & 31;
    const int wib  = threadIdx.x >> 6;
    const int half = lane >> 5;

    const float4 bgv = ld4(&bg[q * 4]);
    const float4 wgi = ld4(&Wg[DD * DD + q * 4]);   // importance row (row 128)
    const float4 wp4 = ld4(&Wp[q * 4]);
    const float  bps = bp[0];
    const int ntiles = (NN + 31) / 32;

    for (int tile = blockIdx.x; tile < ntiles; tile += gridDim.x) {
        const int base = tile * 32 + wib * 8 + half * 4;
        const int n0 = min(base + 0, NN - 1);
        const int n1 = min(base + 1, NN - 1);
        const int n2 = min(base + 2, NN - 1);
        const int n3 = min(base + 3, NN - 1);
        const float* c0 = conv + (size_t)n0 * DD;
        const float* c1 = conv + (size_t)n1 * DD;
        const float* c2 = conv + (size_t)n2 * DD;
        const float* c3 = conv + (size_t)n3 * DD;
        float4 acc0 = bgv, acc1 = bgv, acc2 = bgv, acc3 = bgv;
#pragma unroll 2
        for (int j = 0; j < DD; j += 4) {
            const float4 wv0 = ld4(&sW[(j + 0) * DD + q * 4]);
            const float4 wv1 = ld4(&sW[(j + 1) * DD + q * 4]);
            const float4 wv2 = ld4(&sW[(j + 2) * DD + q * 4]);
            const float4 wv3 = ld4(&sW[(j + 3) * DD + q * 4]);
            float4 cv;
            cv = ld4(c0 + j);
            fma4(acc0, cv.x, wv0); fma4(acc0, cv.y, wv1);
            fma4(acc0, cv.z, wv2); fma4(acc0, cv.w, wv3);
            cv = ld4(c1 + j);
            fma4(acc1, cv.x, wv0); fma4(acc1, cv.y, wv1);
            fma4(acc1, cv.z, wv2); fma4(acc1, cv.w, wv3);
            cv = ld4(c2 + j);
            fma4(acc2, cv.x, wv0); fma4(acc2, cv.y, wv1);
            fma4(acc2, cv.z, wv2); fma4(acc2, cv.w, wv3);
            cv = ld4(c3 + j);
            fma4(acc3, cv.x, wv0); fma4(acc3, cv.y, wv1);
            fma4(acc3, cv.z, wv2); fma4(acc3, cv.w, wv3);
        }

        float s[4];
        const int   ns[4] = {n0, n1, n2, n3};
        float4      as[4] = {acc0, acc1, acc2, acc3};
#pragma unroll
        for (int m = 0; m < 4; ++m) {
            const int n = ns[m];
            float4 a = as[m];
            fma4(a, imp[n], wgi);
            float4 g;
            g.x = 1.0f / (1.0f + expf(-a.x));
            g.y = 1.0f / (1.0f + expf(-a.y));
            g.z = 1.0f / (1.0f + expf(-a.z));
            g.w = 1.0f / (1.0f + expf(-a.w));
            const float4 cv = ld4(&conv[(size_t)n * DD + q * 4]);
            const float4 xv = ld4(&x[(size_t)n * DD + q * 4]);
            float4 o;
            o.x = fmaf(g.x, cv.x - xv.x, xv.x);
            o.y = fmaf(g.y, cv.y - xv.y, xv.y);
            o.z = fmaf(g.z, cv.z - xv.z, xv.z);
            o.w = fmaf(g.w, cv.w - xv.w, xv.w);
            if (base + m < NN)
                *reinterpret_cast<float4*>(&outp[(size_t)n * DD + q * 4]) = o;
            s[m] = o.x * wp4.x + o.y * wp4.y + o.z * wp4.z + o.w * wp4.w;
        }
#pragma unroll
        for (int off = 16; off; off >>= 1) {
            s[0] += __shfl_xor(s[0], off);
            s[1] += __shfl_xor(s[1], off);
            s[2] += __shfl_xor(s[2], off);
            s[3] += __shfl_xor(s[3], off);
        }
        if (q == 0) {
#pragma unroll
            for (int m = 0; m < 4; ++m)
                if (base + m < NN) prop[base + m] = s[m] + bps;
        }
    }
}

extern "C" void kernel_launch(void* const* d_in, const int* in_sizes, int n_in,
                              void* d_out, int out_size, void* d_ws, size_t ws_size,
                              hipStream_t stream) {
    const float* x   = (const float*)d_in[0];
    const int*   ei  = (const int*)d_in[1];
    const float* ea  = (const float*)d_in[2];
    const float* imp = (const float*)d_in[3];
    const float* We  = (const float*)d_in[4];
    const float* be  = (const float*)d_in[5];
    const float* Wc  = (const float*)d_in[6];
    const float* bc  = (const float*)d_in[7];
    const float* Wg  = (const float*)d_in[8];
    const float* bg  = (const float*)d_in[9];
    const float* Wp  = (const float*)d_in[10];
    const float* bp  = (const float*)d_in[11];

    float* out  = (float*)d_out;                 // [NN, DD]
    float* prop = out + (size_t)NN * DD;         // [NN]

    // ws layout
    float* pre    = (float*)d_ws;                               // NN*DD f32
    int*   counts = (int*)((char*)d_ws + 25600000);             // NN
    int*   rowptr = (int*)((char*)d_ws + 25800000);             // NN+1
    int*   cursor = (int*)((char*)d_ws + 26000064);             // NN+1
    int2*  sdat   = (int2*)((char*)d_ws + 26200192);            // NE int2
    const size_t REQ = 26200192 + (size_t)NE * 8;

    if (ws_size >= REQ) {
        hipMemsetAsync(counts, 0, NN * sizeof(int), stream);
        hipLaunchKernelGGL(k_hist,    dim3(2048), dim3(256),  0, stream, ei, counts);
        hipLaunchKernelGGL(k_scan,    dim3(1),    dim3(1024), 0, stream, counts, rowptr, cursor);
        hipLaunchKernelGGL(k_scatter, dim3(2048), dim3(256),  0, stream, ei, cursor, sdat);
        hipLaunchKernelGGL(k_agg,     dim3(4096), dim3(256),  0, stream,
                           x, ea, We, be, rowptr, sdat, pre);
    } else {
        // fallback: atomic scatter path (pre buffer doubles as agg)
        hipMemsetAsync(pre, 0, (size_t)NN * DD * sizeof(float), stream);
        hipLaunchKernelGGL(k_edge_atomic, dim3(4096), dim3(256), 0, stream,
                           x, ei, ea, We, be, pre);
        hipLaunchKernelGGL(k_addx, dim3(2048), dim3(256), 0, stream, x, pre);
    }
    hipLaunchKernelGGL(k_conv, dim3(512), dim3(256), 0, stream, pre, Wc, bc, out);
    hipLaunchKernelGGL(k_gate, dim3(512), dim3(256), 0, stream,
                       x, out, imp, Wg, bg, Wp, bp, out, prop);
}

// Round 4
// 286.963 us; speedup vs baseline: 1.5788x; 1.4122x over previous
//
#include <hip/hip_runtime.h>

#define NN 50000
#define NE 800000
#define DD 128
#define ED 32
#define NB 196   // ceil(NN/256)

typedef short bf16x8 __attribute__((ext_vector_type(8)));
typedef float f32x4  __attribute__((ext_vector_type(4)));

__device__ __forceinline__ float4 ld4(const float* p) {
    return *reinterpret_cast<const float4*>(p);
}
__device__ __forceinline__ void fma4(float4& a, float s, float4 w) {
    a.x = fmaf(s, w.x, a.x);
    a.y = fmaf(s, w.y, a.y);
    a.z = fmaf(s, w.z, a.z);
    a.w = fmaf(s, w.w, a.w);
}
__device__ __forceinline__ short f2bf(float f) {   // RTN-even f32 -> bf16 bits
    unsigned u = __float_as_uint(f);
    u += 0x7fffu + ((u >> 16) & 1u);
    return (short)(u >> 16);
}
__device__ __forceinline__ int sniff64(const int* ei) {
    // int64 indices < 2^32: every odd 32-bit word is zero.
    return ((ei[1] | ei[3] | ei[5] | ei[7]) == 0) ? 1 : 0;
}

// ============================================================ CSR build
__global__ __launch_bounds__(256)
void k_hist(const int* __restrict__ ei, int* __restrict__ counts) {
    const int is64 = sniff64(ei);
    for (int e = blockIdx.x * blockDim.x + threadIdx.x; e < NE;
         e += gridDim.x * blockDim.x) {
        const int dst = ei[(long)(NE + e) << is64];
        atomicAdd(&counts[dst], 1);
    }
}

__global__ __launch_bounds__(256)
void k_bsum(const int* __restrict__ counts, int* __restrict__ bsum) {
    const int i = blockIdx.x * 256 + threadIdx.x;
    int c = (i < NN) ? counts[i] : 0;
#pragma unroll
    for (int off = 32; off; off >>= 1) c += __shfl_xor(c, off, 64);
    __shared__ int ws4[4];
    if ((threadIdx.x & 63) == 0) ws4[threadIdx.x >> 6] = c;
    __syncthreads();
    if (threadIdx.x == 0) bsum[blockIdx.x] = ws4[0] + ws4[1] + ws4[2] + ws4[3];
}

__global__ __launch_bounds__(256)
void k_scanb(const int* __restrict__ bsum, int* __restrict__ bexcl) {
    const int tid = threadIdx.x, lane = tid & 63, w = tid >> 6;
    const int v = (tid < NB) ? bsum[tid] : 0;
    int s = v;
#pragma unroll
    for (int off = 1; off < 64; off <<= 1) {
        const int t = __shfl_up(s, off, 64);
        if (lane >= off) s += t;
    }
    __shared__ int wsum[4], wexcl[4];
    if (lane == 63) wsum[w] = s;
    __syncthreads();
    if (tid == 0) {
        int r = 0;
#pragma unroll
        for (int k = 0; k < 4; ++k) { wexcl[k] = r; r += wsum[k]; }
    }
    __syncthreads();
    if (tid < NB) bexcl[tid] = wexcl[w] + s - v;
}

__global__ __launch_bounds__(256)
void k_rowptr(const int* __restrict__ counts, const int* __restrict__ bexcl,
              int* __restrict__ rowptr, int* __restrict__ cursor) {
    const int tid = threadIdx.x, lane = tid & 63, w = tid >> 6;
    const int i = blockIdx.x * 256 + tid;
    const int c = (i < NN) ? counts[i] : 0;
    int s = c;
#pragma unroll
    for (int off = 1; off < 64; off <<= 1) {
        const int t = __shfl_up(s, off, 64);
        if (lane >= off) s += t;
    }
    __shared__ int wsum[4], wexcl[4];
    if (lane == 63) wsum[w] = s;
    __syncthreads();
    if (tid == 0) {
        int r = 0;
#pragma unroll
        for (int k = 0; k < 4; ++k) { wexcl[k] = r; r += wsum[k]; }
    }
    __syncthreads();
    const int excl = bexcl[blockIdx.x] + wexcl[w] + s - c;
    if (i < NN) { rowptr[i] = excl; cursor[i] = excl; }
    if (blockIdx.x == 0 && tid == 0) rowptr[NN] = NE;
}

__global__ __launch_bounds__(256)
void k_scatter(const int* __restrict__ ei, int* __restrict__ cursor,
               int2* __restrict__ sdat) {
    const int is64 = sniff64(ei);
    for (int e = blockIdx.x * blockDim.x + threadIdx.x; e < NE;
         e += gridDim.x * blockDim.x) {
        const int src = ei[(long)e << is64];
        const int dst = ei[(long)(NE + e) << is64];
        const int pos = atomicAdd(&cursor[dst], 1);
        sdat[pos] = make_int2(src, e);
    }
}

// ============================================================ aggregation
// One wave per node. Per 16-edge chunk: A = 16 ea rows (bf16), B = We
// (resident bf16 fragments), 8x mfma_f32_16x16x32_bf16 computes e[m][d]
// for all 16 edges x 128 dims with C initialized to be[d]. Epilogue does
// f32 relu(x[src]+e) with pad masking, reduces over edges in-wave.
// C/D layout: lane l, reg r -> D[edge (l>>4)*4+r][dim 16b+(l&15)].
__global__ __launch_bounds__(256, 4)
void k_agg(const float* __restrict__ x, const float* __restrict__ ea,
           const float* __restrict__ We, const float* __restrict__ be,
           const int* __restrict__ rowptr, const int2* __restrict__ sdat,
           float* __restrict__ pre)
{
    const int lane = threadIdx.x & 63;
    const int wid  = (blockIdx.x << 2) | (threadIdx.x >> 6);
    const int nw   = gridDim.x << 2;
    const int ncol = lane & 15;
    const int krow = (lane >> 4) << 3;   // 0,8,16,24
    const int grp  = lane >> 4;

    // B fragments: Bf[b][i] = We[krow+i][16b+ncol]; be folded into C-init.
    bf16x8 Bf[8];
    float beb[8];
#pragma unroll
    for (int b = 0; b < 8; ++b) {
#pragma unroll
        for (int i = 0; i < 8; ++i)
            Bf[b][i] = f2bf(We[(krow + i) * DD + b * 16 + ncol]);
        beb[b] = be[b * 16 + ncol];
    }

    for (int n = wid; n < NN; n += nw) {
        const int beg = rowptr[n], end = rowptr[n + 1];
        float a0 = 0.0f, a1 = 0.0f;

        for (int cb = beg; cb < end; cb += 16) {
            const int cnt = min(16, end - cb);
            int2 dv = make_int2(0, 0);
            if (lane < cnt) dv = sdat[cb + lane];

            // A fragment: edge row (lane&15), k = krow..krow+7 (8 consec f32)
            const int eidx = __shfl(dv.y, ncol, 64);
            const float* ear = ea + (size_t)eidx * ED + krow;
            const float4 r0 = ld4(ear);
            const float4 r1 = ld4(ear + 4);
            bf16x8 Af;
            Af[0] = f2bf(r0.x); Af[1] = f2bf(r0.y);
            Af[2] = f2bf(r0.z); Af[3] = f2bf(r0.w);
            Af[4] = f2bf(r1.x); Af[5] = f2bf(r1.y);
            Af[6] = f2bf(r1.z); Af[7] = f2bf(r1.w);

            // x-gather bases + pad masks for this lane's 4 edge rows
            const float* xr[4];
            float mv[4];
#pragma unroll
            for (int r = 0; r < 4; ++r) {
                const int m = (grp << 2) + r;
                const int srcm = __shfl(dv.x, m, 64);
                xr[r] = x + (size_t)srcm * DD + ncol;
                mv[r] = (m < cnt) ? 1.0f : 0.0f;
            }
            // prefetch all 32 x values (in flight under the MFMAs)
            float xv[8][4];
#pragma unroll
            for (int b = 0; b < 8; ++b)
#pragma unroll
                for (int r = 0; r < 4; ++r)
                    xv[b][r] = xr[r][b * 16];

            f32x4 C[8];
#pragma unroll
            for (int b = 0; b < 8; ++b) {
                f32x4 c0 = { beb[b], beb[b], beb[b], beb[b] };
                C[b] = __builtin_amdgcn_mfma_f32_16x16x32_bf16(Af, Bf[b], c0, 0, 0, 0);
            }

            float red[8];
#pragma unroll
            for (int b = 0; b < 8; ++b) {
                float t = 0.0f;
#pragma unroll
                for (int r = 0; r < 4; ++r)
                    t += fmaxf(xv[b][r] + C[b][r], 0.0f) * mv[r];
                t += __shfl_xor(t, 16, 64);
                t += __shfl_xor(t, 32, 64);
                red[b] = t;
            }

            float v0 = red[0], v1 = red[4];
            v0 = (grp == 1) ? red[1] : v0;
            v0 = (grp == 2) ? red[2] : v0;
            v0 = (grp == 3) ? red[3] : v0;
            v1 = (grp == 1) ? red[5] : v1;
            v1 = (grp == 2) ? red[6] : v1;
            v1 = (grp == 3) ? red[7] : v1;
            a0 += v0; a1 += v1;
        }
        pre[(size_t)n * DD + lane]      = a0 + x[(size_t)n * DD + lane];
        pre[(size_t)n * DD + 64 + lane] = a1 + x[(size_t)n * DD + 64 + lane];
    }
}

// ============================================================ conv stage
__global__ __launch_bounds__(256, 2)
void k_conv(const float* __restrict__ pre, const float* __restrict__ Wc,
            const float* __restrict__ bc, float* __restrict__ conv)
{
    __shared__ float sW[DD * DD];
    for (int i = threadIdx.x * 4; i < DD * DD; i += 1024)
        *reinterpret_cast<float4*>(&sW[i]) = ld4(&Wc[i]);
    __syncthreads();

    const int lane = threadIdx.x & 63;
    const int q    = lane & 31;
    const int wib  = threadIdx.x >> 6;
    const int half = lane >> 5;

    const float4 bcv = ld4(&bc[q * 4]);
    const int ntiles = (NN + 31) / 32;

    for (int tile = blockIdx.x; tile < ntiles; tile += gridDim.x) {
        const int base = tile * 32 + wib * 8 + half * 4;
        const int n0 = min(base + 0, NN - 1);
        const int n1 = min(base + 1, NN - 1);
        const int n2 = min(base + 2, NN - 1);
        const int n3 = min(base + 3, NN - 1);
        const float* p0 = pre + (size_t)n0 * DD;
        const float* p1 = pre + (size_t)n1 * DD;
        const float* p2 = pre + (size_t)n2 * DD;
        const float* p3 = pre + (size_t)n3 * DD;
        float4 acc0 = bcv, acc1 = bcv, acc2 = bcv, acc3 = bcv;
#pragma unroll 2
        for (int j = 0; j < DD; j += 4) {
            const float4 wv0 = ld4(&sW[(j + 0) * DD + q * 4]);
            const float4 wv1 = ld4(&sW[(j + 1) * DD + q * 4]);
            const float4 wv2 = ld4(&sW[(j + 2) * DD + q * 4]);
            const float4 wv3 = ld4(&sW[(j + 3) * DD + q * 4]);
            float4 v;
            v = ld4(p0 + j);
            fma4(acc0, v.x, wv0); fma4(acc0, v.y, wv1);
            fma4(acc0, v.z, wv2); fma4(acc0, v.w, wv3);
            v = ld4(p1 + j);
            fma4(acc1, v.x, wv0); fma4(acc1, v.y, wv1);
            fma4(acc1, v.z, wv2); fma4(acc1, v.w, wv3);
            v = ld4(p2 + j);
            fma4(acc2, v.x, wv0); fma4(acc2, v.y, wv1);
            fma4(acc2, v.z, wv2); fma4(acc2, v.w, wv3);
            v = ld4(p3 + j);
            fma4(acc3, v.x, wv0); fma4(acc3, v.y, wv1);
            fma4(acc3, v.z, wv2); fma4(acc3, v.w, wv3);
        }
        if (base + 0 < NN) *reinterpret_cast<float4*>(&conv[(size_t)n0 * DD + q * 4]) = acc0;
        if (base + 1 < NN) *reinterpret_cast<float4*>(&conv[(size_t)n1 * DD + q * 4]) = acc1;
        if (base + 2 < NN) *reinterpret_cast<float4*>(&conv[(size_t)n2 * DD + q * 4]) = acc2;
        if (base + 3 < NN) *reinterpret_cast<float4*>(&conv[(size_t)n3 * DD + q * 4]) = acc3;
    }
}

// ============================================================ gate stage
__global__ __launch_bounds__(256, 2)
void k_gate(const float* __restrict__ x, const float* conv,
            const float* __restrict__ imp, const float* __restrict__ Wg,
            const float* __restrict__ bg, const float* __restrict__ Wp,
            const float* __restrict__ bp, float* outp, float* __restrict__ prop)
{
    __shared__ float sW[DD * DD];
    for (int i = threadIdx.x * 4; i < DD * DD; i += 1024)
        *reinterpret_cast<float4*>(&sW[i]) = ld4(&Wg[i]);   // rows 0..127
    __syncthreads();

    const int lane = threadIdx.x & 63;
    const int q    = lane & 31;
    const int wib  = threadIdx.x >> 6;
    const int half = lane >> 5;

    const float4 bgv = ld4(&bg[q * 4]);
    const float4 wgi = ld4(&Wg[DD * DD + q * 4]);   // importance row (row 128)
    const float4 wp4 = ld4(&Wp[q * 4]);
    const float  bps = bp[0];
    const int ntiles = (NN + 31) / 32;

    for (int tile = blockIdx.x; tile < ntiles; tile += gridDim.x) {
        const int base = tile * 32 + wib * 8 + half * 4;
        const int n0 = min(base + 0, NN - 1);
        const int n1 = min(base + 1, NN - 1);
        const int n2 = min(base + 2, NN - 1);
        const int n3 = min(base + 3, NN - 1);
        const float* c0 = conv + (size_t)n0 * DD;
        const float* c1 = conv + (size_t)n1 * DD;
        const float* c2 = conv + (size_t)n2 * DD;
        const float* c3 = conv + (size_t)n3 * DD;
        float4 acc0 = bgv, acc1 = bgv, acc2 = bgv, acc3 = bgv;
#pragma unroll 2
        for (int j = 0; j < DD; j += 4) {
            const float4 wv0 = ld4(&sW[(j + 0) * DD + q * 4]);
            const float4 wv1 = ld4(&sW[(j + 1) * DD + q * 4]);
            const float4 wv2 = ld4(&sW[(j + 2) * DD + q * 4]);
            const float4 wv3 = ld4(&sW[(j + 3) * DD + q * 4]);
            float4 cv;
            cv = ld4(c0 + j);
            fma4(acc0, cv.x, wv0); fma4(acc0, cv.y, wv1);
            fma4(acc0, cv.z, wv2); fma4(acc0, cv.w, wv3);
            cv = ld4(c1 + j);
            fma4(acc1, cv.x, wv0); fma4(acc1, cv.y, wv1);
            fma4(acc1, cv.z, wv2); fma4(acc1, cv.w, wv3);
            cv = ld4(c2 + j);
            fma4(acc2, cv.x, wv0); fma4(acc2, cv.y, wv1);
            fma4(acc2, cv.z, wv2); fma4(acc2, cv.w, wv3);
            cv = ld4(c3 + j);
            fma4(acc3, cv.x, wv0); fma4(acc3, cv.y, wv1);
            fma4(acc3, cv.z, wv2); fma4(acc3, cv.w, wv3);
        }

        float s[4];
        const int   ns[4] = {n0, n1, n2, n3};
        float4      as[4] = {acc0, acc1, acc2, acc3};
#pragma unroll
        for (int m = 0; m < 4; ++m) {
            const int n = ns[m];
            float4 a = as[m];
            fma4(a, imp[n], wgi);
            float4 g;
            g.x = 1.0f / (1.0f + expf(-a.x));
            g.y = 1.0f / (1.0f + expf(-a.y));
            g.z = 1.0f / (1.0f + expf(-a.z));
            g.w = 1.0f / (1.0f + expf(-a.w));
            const float4 cv = ld4(&conv[(size_t)n * DD + q * 4]);
            const float4 xv = ld4(&x[(size_t)n * DD + q * 4]);
            float4 o;
            o.x = fmaf(g.x, cv.x - xv.x, xv.x);
            o.y = fmaf(g.y, cv.y - xv.y, xv.y);
            o.z = fmaf(g.z, cv.z - xv.z, xv.z);
            o.w = fmaf(g.w, cv.w - xv.w, xv.w);
            if (base + m < NN)
                *reinterpret_cast<float4*>(&outp[(size_t)n * DD + q * 4]) = o;
            s[m] = o.x * wp4.x + o.y * wp4.y + o.z * wp4.z + o.w * wp4.w;
        }
#pragma unroll
        for (int off = 16; off; off >>= 1) {
            s[0] += __shfl_xor(s[0], off);
            s[1] += __shfl_xor(s[1], off);
            s[2] += __shfl_xor(s[2], off);
            s[3] += __shfl_xor(s[3], off);
        }
        if (q == 0) {
#pragma unroll
            for (int m = 0; m < 4; ++m)
                if (base + m < NN) prop[base + m] = s[m] + bps;
        }
    }
}

extern "C" void kernel_launch(void* const* d_in, const int* in_sizes, int n_in,
                              void* d_out, int out_size, void* d_ws, size_t ws_size,
                              hipStream_t stream) {
    const float* x   = (const float*)d_in[0];
    const int*   ei  = (const int*)d_in[1];
    const float* ea  = (const float*)d_in[2];
    const float* imp = (const float*)d_in[3];
    const float* We  = (const float*)d_in[4];
    const float* be  = (const float*)d_in[5];
    const float* Wc  = (const float*)d_in[6];
    const float* bc  = (const float*)d_in[7];
    const float* Wg  = (const float*)d_in[8];
    const float* bg  = (const float*)d_in[9];
    const float* Wp  = (const float*)d_in[10];
    const float* bp  = (const float*)d_in[11];

    float* out  = (float*)d_out;                 // [NN, DD]
    float* prop = out + (size_t)NN * DD;         // [NN]

    // ws layout (same footprint as round 3, known to fit)
    float* pre    = (float*)d_ws;                               // NN*DD f32
    int*   bsum   = (int*)d_ws;                                 // NB (dead before k_agg)
    int*   bexcl  = (int*)((char*)d_ws + 4096);                 // NB (dead before k_agg)
    int*   counts = (int*)((char*)d_ws + 25600000);             // NN
    int*   rowptr = (int*)((char*)d_ws + 25800000);             // NN+1
    int*   cursor = (int*)((char*)d_ws + 26000064);             // NN
    int2*  sdat   = (int2*)((char*)d_ws + 26200192);            // NE int2

    hipMemsetAsync(counts, 0, NN * sizeof(int), stream);
    hipLaunchKernelGGL(k_hist,    dim3(2048),  dim3(256), 0, stream, ei, counts);
    hipLaunchKernelGGL(k_bsum,    dim3(NB),    dim3(256), 0, stream, counts, bsum);
    hipLaunchKernelGGL(k_scanb,   dim3(1),     dim3(256), 0, stream, bsum, bexcl);
    hipLaunchKernelGGL(k_rowptr,  dim3(NB),    dim3(256), 0, stream, counts, bexcl, rowptr, cursor);
    hipLaunchKernelGGL(k_scatter, dim3(2048),  dim3(256), 0, stream, ei, cursor, sdat);
    hipLaunchKernelGGL(k_agg,     dim3(12500), dim3(256), 0, stream,
                       x, ea, We, be, rowptr, sdat, pre);
    hipLaunchKernelGGL(k_conv,    dim3(512),   dim3(256), 0, stream, pre, Wc, bc, out);
    hipLaunchKernelGGL(k_gate,    dim3(512),   dim3(256), 0, stream,
                       x, out, imp, Wg, bg, Wp, bp, out, prop);
}

// Round 5
// 231.433 us; speedup vs baseline: 1.9576x; 1.2399x over previous
//
#include <hip/hip_runtime.h>

#define NN 50000
#define NE 800000
#define DD 128
#define ED 32
#define NB 196   // ceil(NN/256)

typedef short bf16x8 __attribute__((ext_vector_type(8)));
typedef float f32x4  __attribute__((ext_vector_type(4)));

__device__ __forceinline__ float4 ld4(const float* p) {
    return *reinterpret_cast<const float4*>(p);
}
__device__ __forceinline__ short f2bf(float f) {   // RTN-even f32 -> bf16 bits
    unsigned u = __float_as_uint(f);
    u += 0x7fffu + ((u >> 16) & 1u);
    return (short)(u >> 16);
}
__device__ __forceinline__ float bf2f(short h) {
    return __uint_as_float(((unsigned)(unsigned short)h) << 16);
}
__device__ __forceinline__ int sniff64(const int* ei) {
    // int64 indices < 2^32: every odd 32-bit word is zero.
    return ((ei[1] | ei[3] | ei[5] | ei[7]) == 0) ? 1 : 0;
}

// ============================================================ CSR build
__global__ __launch_bounds__(256)
void k_hist(const int* __restrict__ ei, int* __restrict__ counts) {
    const int is64 = sniff64(ei);
    for (int e = blockIdx.x * blockDim.x + threadIdx.x; e < NE;
         e += gridDim.x * blockDim.x) {
        const int dst = ei[(long)(NE + e) << is64];
        atomicAdd(&counts[dst], 1);
    }
}

__global__ __launch_bounds__(256)
void k_bsum(const int* __restrict__ counts, int* __restrict__ bsum) {
    const int i = blockIdx.x * 256 + threadIdx.x;
    int c = (i < NN) ? counts[i] : 0;
#pragma unroll
    for (int off = 32; off; off >>= 1) c += __shfl_xor(c, off, 64);
    __shared__ int ws4[4];
    if ((threadIdx.x & 63) == 0) ws4[threadIdx.x >> 6] = c;
    __syncthreads();
    if (threadIdx.x == 0) bsum[blockIdx.x] = ws4[0] + ws4[1] + ws4[2] + ws4[3];
}

__global__ __launch_bounds__(256)
void k_scanb(const int* __restrict__ bsum, int* __restrict__ bexcl) {
    const int tid = threadIdx.x, lane = tid & 63, w = tid >> 6;
    const int v = (tid < NB) ? bsum[tid] : 0;
    int s = v;
#pragma unroll
    for (int off = 1; off < 64; off <<= 1) {
        const int t = __shfl_up(s, off, 64);
        if (lane >= off) s += t;
    }
    __shared__ int wsum[4], wexcl[4];
    if (lane == 63) wsum[w] = s;
    __syncthreads();
    if (tid == 0) {
        int r = 0;
#pragma unroll
        for (int k = 0; k < 4; ++k) { wexcl[k] = r; r += wsum[k]; }
    }
    __syncthreads();
    if (tid < NB) bexcl[tid] = wexcl[w] + s - v;
}

__global__ __launch_bounds__(256)
void k_rowptr(const int* __restrict__ counts, const int* __restrict__ bexcl,
              int* __restrict__ rowptr, int* __restrict__ cursor) {
    const int tid = threadIdx.x, lane = tid & 63, w = tid >> 6;
    const int i = blockIdx.x * 256 + tid;
    const int c = (i < NN) ? counts[i] : 0;
    int s = c;
#pragma unroll
    for (int off = 1; off < 64; off <<= 1) {
        const int t = __shfl_up(s, off, 64);
        if (lane >= off) s += t;
    }
    __shared__ int wsum[4], wexcl[4];
    if (lane == 63) wsum[w] = s;
    __syncthreads();
    if (tid == 0) {
        int r = 0;
#pragma unroll
        for (int k = 0; k < 4; ++k) { wexcl[k] = r; r += wsum[k]; }
    }
    __syncthreads();
    const int excl = bexcl[blockIdx.x] + wexcl[w] + s - c;
    if (i < NN) { rowptr[i] = excl; cursor[i] = excl; }
    if (blockIdx.x == 0 && tid == 0) rowptr[NN] = NE;
}

__global__ __launch_bounds__(256)
void k_scatter(const int* __restrict__ ei, int* __restrict__ cursor,
               int2* __restrict__ sdat) {
    const int is64 = sniff64(ei);
    for (int e = blockIdx.x * blockDim.x + threadIdx.x; e < NE;
         e += gridDim.x * blockDim.x) {
        const int src = ei[(long)e << is64];
        const int dst = ei[(long)(NE + e) << is64];
        const int pos = atomicAdd(&cursor[dst], 1);
        sdat[pos] = make_int2(src, e);
    }
}

// ============================================================ aggregation
// One wave handles TWO nodes (wid, wid+25000) with fully interleaved
// independent pipelines (2x memory-level parallelism). Per 16-edge chunk:
// C-init = x[src_m][d] (the accumulator IS the gathered x row), then
// 8x mfma_f32_16x16x32_bf16 adds ea@We on top; epilogue does
// relu(C + be)*mask, reduces over the 16 edges in-wave. No atomics.
__global__ __launch_bounds__(256, 2)
void k_agg(const float* __restrict__ x, const float* __restrict__ ea,
           const float* __restrict__ We, const float* __restrict__ be,
           const int* __restrict__ rowptr, const int2* __restrict__ sdat,
           float* __restrict__ pre)
{
    const int lane = threadIdx.x & 63;
    const int wid  = (blockIdx.x << 2) | (threadIdx.x >> 6);   // 0..24999
    const int ncol = lane & 15;
    const int krow = (lane >> 4) << 3;   // 0,8,16,24
    const int grp  = lane >> 4;

    // B fragments: Bf[b][i] = We[krow+i][16b+ncol]
    bf16x8 Bf[8];
    float beb[8];
#pragma unroll
    for (int b = 0; b < 8; ++b) {
#pragma unroll
        for (int i = 0; i < 8; ++i)
            Bf[b][i] = f2bf(We[(krow + i) * DD + b * 16 + ncol]);
        beb[b] = be[b * 16 + ncol];
    }

    const int nA = wid, nB = wid + NN / 2;
    int cbA = rowptr[nA]; const int endA = rowptr[nA + 1];
    int cbB = rowptr[nB]; const int endB = rowptr[nB + 1];
    float aA0 = 0.f, aA1 = 0.f, aB0 = 0.f, aB1 = 0.f;

    while (cbA < endA || cbB < endB) {
        const bool dA = cbA < endA, dB = cbB < endB;
        const int cntA = dA ? min(16, endA - cbA) : 0;
        const int cntB = dB ? min(16, endB - cbB) : 0;
        int2 dvA = make_int2(0, 0), dvB = make_int2(0, 0);
        if (dA && lane < cntA) dvA = sdat[cbA + lane];
        if (dB && lane < cntB) dvB = sdat[cbB + lane];

        bf16x8 AfA = {}, AfB = {};
        f32x4 CA[8], CB[8];
        float mA[4], mB[4];

        if (dA) {
            const int eidx = __shfl(dvA.y, ncol, 64);
            const float* ear = ea + (size_t)eidx * ED + krow;
            const float4 r0 = ld4(ear), r1 = ld4(ear + 4);
            AfA[0] = f2bf(r0.x); AfA[1] = f2bf(r0.y);
            AfA[2] = f2bf(r0.z); AfA[3] = f2bf(r0.w);
            AfA[4] = f2bf(r1.x); AfA[5] = f2bf(r1.y);
            AfA[6] = f2bf(r1.z); AfA[7] = f2bf(r1.w);
            const float* xr[4];
#pragma unroll
            for (int r = 0; r < 4; ++r) {
                const int m = (grp << 2) + r;
                xr[r] = x + (size_t)__shfl(dvA.x, m, 64) * DD + ncol;
                mA[r] = (m < cntA) ? 1.0f : 0.0f;
            }
#pragma unroll
            for (int b = 0; b < 8; ++b) {
                f32x4 c;
                c[0] = xr[0][b * 16]; c[1] = xr[1][b * 16];
                c[2] = xr[2][b * 16]; c[3] = xr[3][b * 16];
                CA[b] = c;
            }
        }
        if (dB) {
            const int eidx = __shfl(dvB.y, ncol, 64);
            const float* ear = ea + (size_t)eidx * ED + krow;
            const float4 r0 = ld4(ear), r1 = ld4(ear + 4);
            AfB[0] = f2bf(r0.x); AfB[1] = f2bf(r0.y);
            AfB[2] = f2bf(r0.z); AfB[3] = f2bf(r0.w);
            AfB[4] = f2bf(r1.x); AfB[5] = f2bf(r1.y);
            AfB[6] = f2bf(r1.z); AfB[7] = f2bf(r1.w);
            const float* xr[4];
#pragma unroll
            for (int r = 0; r < 4; ++r) {
                const int m = (grp << 2) + r;
                xr[r] = x + (size_t)__shfl(dvB.x, m, 64) * DD + ncol;
                mB[r] = (m < cntB) ? 1.0f : 0.0f;
            }
#pragma unroll
            for (int b = 0; b < 8; ++b) {
                f32x4 c;
                c[0] = xr[0][b * 16]; c[1] = xr[1][b * 16];
                c[2] = xr[2][b * 16]; c[3] = xr[3][b * 16];
                CB[b] = c;
            }
        }

        if (dA) {
#pragma unroll
            for (int b = 0; b < 8; ++b)
                CA[b] = __builtin_amdgcn_mfma_f32_16x16x32_bf16(AfA, Bf[b], CA[b], 0, 0, 0);
        }
        if (dB) {
#pragma unroll
            for (int b = 0; b < 8; ++b)
                CB[b] = __builtin_amdgcn_mfma_f32_16x16x32_bf16(AfB, Bf[b], CB[b], 0, 0, 0);
        }

        if (dA) {
            float red[8];
#pragma unroll
            for (int b = 0; b < 8; ++b) {
                float t = fmaxf(CA[b][0] + beb[b], 0.f) * mA[0]
                        + fmaxf(CA[b][1] + beb[b], 0.f) * mA[1]
                        + fmaxf(CA[b][2] + beb[b], 0.f) * mA[2]
                        + fmaxf(CA[b][3] + beb[b], 0.f) * mA[3];
                t += __shfl_xor(t, 16, 64);
                t += __shfl_xor(t, 32, 64);
                red[b] = t;
            }
            float v0 = red[0], v1 = red[4];
            v0 = (grp == 1) ? red[1] : v0;
            v0 = (grp == 2) ? red[2] : v0;
            v0 = (grp == 3) ? red[3] : v0;
            v1 = (grp == 1) ? red[5] : v1;
            v1 = (grp == 2) ? red[6] : v1;
            v1 = (grp == 3) ? red[7] : v1;
            aA0 += v0; aA1 += v1;
            cbA += 16;
        }
        if (dB) {
            float red[8];
#pragma unroll
            for (int b = 0; b < 8; ++b) {
                float t = fmaxf(CB[b][0] + beb[b], 0.f) * mB[0]
                        + fmaxf(CB[b][1] + beb[b], 0.f) * mB[1]
                        + fmaxf(CB[b][2] + beb[b], 0.f) * mB[2]
                        + fmaxf(CB[b][3] + beb[b], 0.f) * mB[3];
                t += __shfl_xor(t, 16, 64);
                t += __shfl_xor(t, 32, 64);
                red[b] = t;
            }
            float v0 = red[0], v1 = red[4];
            v0 = (grp == 1) ? red[1] : v0;
            v0 = (grp == 2) ? red[2] : v0;
            v0 = (grp == 3) ? red[3] : v0;
            v1 = (grp == 1) ? red[5] : v1;
            v1 = (grp == 2) ? red[6] : v1;
            v1 = (grp == 3) ? red[7] : v1;
            aB0 += v0; aB1 += v1;
            cbB += 16;
        }
    }

    {
        const size_t oA = (size_t)nA * DD;
        pre[oA + lane]      = aA0 + x[oA + lane];
        pre[oA + 64 + lane] = aA1 + x[oA + 64 + lane];
        const size_t oB = (size_t)nB * DD;
        pre[oB + lane]      = aB0 + x[oB + lane];
        pre[oB + 64 + lane] = aB1 + x[oB + 64 + lane];
    }
}

// ============================================================ conv (MFMA)
// conv = pre @ Wc + bc via split-bf16 (hi+lo, 3 MFMAs per tile product).
// Wc staged once in LDS in FRAGMENT ORDER (hi and lo planes) so each
// (kk,b) B-fragment is one conflict-free ds_read_b128 per plane.
// Wave computes 16 nodes; 3125 tiles exactly (50000 = 16*3125).
__global__ __launch_bounds__(256)
void k_conv(const float* __restrict__ pre, const float* __restrict__ Wc,
            const float* __restrict__ bc, float* __restrict__ conv)
{
    __shared__ short sBh[2048 * 8];
    __shared__ short sBl[2048 * 8];
    for (int idx = threadIdx.x; idx < 2048; idx += 256) {
        const int kk = idx >> 9;
        const int b  = (idx >> 6) & 7;
        const int l  = idx & 63;
        const int row0 = kk * 32 + ((l >> 4) << 3);
        const int col  = b * 16 + (l & 15);
        bf16x8 h8, l8;
#pragma unroll
        for (int j = 0; j < 8; ++j) {
            const float v = Wc[(row0 + j) * DD + col];
            const short h = f2bf(v);
            h8[j] = h;
            l8[j] = f2bf(v - bf2f(h));
        }
        *reinterpret_cast<bf16x8*>(&sBh[idx * 8]) = h8;
        *reinterpret_cast<bf16x8*>(&sBl[idx * 8]) = l8;
    }
    __syncthreads();

    const int lane = threadIdx.x & 63;
    const int ncol = lane & 15;
    const int krow = (lane >> 4) << 3;
    const int grp  = lane >> 4;
    const int wid  = (blockIdx.x << 2) | (threadIdx.x >> 6);
    if (wid >= NN / 16) return;

    float bcb[8];
#pragma unroll
    for (int b = 0; b < 8; ++b) bcb[b] = bc[b * 16 + ncol];

    const int m0 = wid * 16;
    const float* arow = pre + (size_t)(m0 + ncol) * DD + krow;

    f32x4 C[8];
#pragma unroll
    for (int b = 0; b < 8; ++b) {
        f32x4 c = { bcb[b], bcb[b], bcb[b], bcb[b] };
        C[b] = c;
    }

#pragma unroll
    for (int kk = 0; kk < 4; ++kk) {
        const float4 a0 = ld4(arow + kk * 32);
        const float4 a1 = ld4(arow + kk * 32 + 4);
        const float av[8] = { a0.x, a0.y, a0.z, a0.w, a1.x, a1.y, a1.z, a1.w };
        bf16x8 Ah, Al;
#pragma unroll
        for (int j = 0; j < 8; ++j) {
            const short h = f2bf(av[j]);
            Ah[j] = h;
            Al[j] = f2bf(av[j] - bf2f(h));
        }
#pragma unroll
        for (int b = 0; b < 8; ++b) {
            const bf16x8 Bh = *reinterpret_cast<const bf16x8*>(&sBh[((kk * 8 + b) * 64 + lane) * 8]);
            const bf16x8 Bl = *reinterpret_cast<const bf16x8*>(&sBl[((kk * 8 + b) * 64 + lane) * 8]);
            C[b] = __builtin_amdgcn_mfma_f32_16x16x32_bf16(Ah, Bh, C[b], 0, 0, 0);
            C[b] = __builtin_amdgcn_mfma_f32_16x16x32_bf16(Al, Bh, C[b], 0, 0, 0);
            C[b] = __builtin_amdgcn_mfma_f32_16x16x32_bf16(Ah, Bl, C[b], 0, 0, 0);
        }
    }

#pragma unroll
    for (int r = 0; r < 4; ++r) {
        float* crow = conv + (size_t)(m0 + (grp << 2) + r) * DD + ncol;
#pragma unroll
        for (int b = 0; b < 8; ++b) crow[b * 16] = C[b][r];
    }
}

// ============================================================ gate (MFMA)
// gate = sigmoid(conv @ Wg[0:128] + imp*Wg[128] + bg); out = x + g*(conv-x);
// prop = out @ Wp + bp.  Same split-bf16 GEMM structure as k_conv.
// conv read from d_out and overwritten in place (reads precede writes).
__global__ __launch_bounds__(256)
void k_gate(const float* __restrict__ x, const float* conv,
            const float* __restrict__ imp, const float* __restrict__ Wg,
            const float* __restrict__ bg, const float* __restrict__ Wp,
            const float* __restrict__ bp, float* outp, float* __restrict__ prop)
{
    __shared__ short sBh[2048 * 8];
    __shared__ short sBl[2048 * 8];
    for (int idx = threadIdx.x; idx < 2048; idx += 256) {
        const int kk = idx >> 9;
        const int b  = (idx >> 6) & 7;
        const int l  = idx & 63;
        const int row0 = kk * 32 + ((l >> 4) << 3);
        const int col  = b * 16 + (l & 15);
        bf16x8 h8, l8;
#pragma unroll
        for (int j = 0; j < 8; ++j) {
            const float v = Wg[(row0 + j) * DD + col];
            const short h = f2bf(v);
            h8[j] = h;
            l8[j] = f2bf(v - bf2f(h));
        }
        *reinterpret_cast<bf16x8*>(&sBh[idx * 8]) = h8;
        *reinterpret_cast<bf16x8*>(&sBl[idx * 8]) = l8;
    }
    __syncthreads();

    const int lane = threadIdx.x & 63;
    const int ncol = lane & 15;
    const int krow = (lane >> 4) << 3;
    const int grp  = lane >> 4;
    const int wid  = (blockIdx.x << 2) | (threadIdx.x >> 6);
    if (wid >= NN / 16) return;

    float bgb[8], wgi[8], wp8[8];
#pragma unroll
    for (int b = 0; b < 8; ++b) {
        bgb[b] = bg[b * 16 + ncol];
        wgi[b] = Wg[DD * DD + b * 16 + ncol];   // importance row (row 128)
        wp8[b] = Wp[b * 16 + ncol];
    }
    const float bps = bp[0];

    const int m0 = wid * 16;

    // preload conv & x in D-pattern (for blend) + imp — in flight under GEMM
    float cvD[8][4], xvD[8][4], im[4];
#pragma unroll
    for (int r = 0; r < 4; ++r) {
        const int m = m0 + (grp << 2) + r;
        const float* cr = conv + (size_t)m * DD + ncol;
        const float* xr = x    + (size_t)m * DD + ncol;
        im[r] = imp[m];
#pragma unroll
        for (int b = 0; b < 8; ++b) { cvD[b][r] = cr[b * 16]; xvD[b][r] = xr[b * 16]; }
    }

    f32x4 C[8];
#pragma unroll
    for (int b = 0; b < 8; ++b) {
        f32x4 c = { bgb[b], bgb[b], bgb[b], bgb[b] };
        C[b] = c;
    }

    const float* arow = conv + (size_t)(m0 + ncol) * DD + krow;
#pragma unroll
    for (int kk = 0; kk < 4; ++kk) {
        const float4 a0 = ld4(arow + kk * 32);
        const float4 a1 = ld4(arow + kk * 32 + 4);
        const float av[8] = { a0.x, a0.y, a0.z, a0.w, a1.x, a1.y, a1.z, a1.w };
        bf16x8 Ah, Al;
#pragma unroll
        for (int j = 0; j < 8; ++j) {
            const short h = f2bf(av[j]);
            Ah[j] = h;
            Al[j] = f2bf(av[j] - bf2f(h));
        }
#pragma unroll
        for (int b = 0; b < 8; ++b) {
            const bf16x8 Bh = *reinterpret_cast<const bf16x8*>(&sBh[((kk * 8 + b) * 64 + lane) * 8]);
            const bf16x8 Bl = *reinterpret_cast<const bf16x8*>(&sBl[((kk * 8 + b) * 64 + lane) * 8]);
            C[b] = __builtin_amdgcn_mfma_f32_16x16x32_bf16(Ah, Bh, C[b], 0, 0, 0);
            C[b] = __builtin_amdgcn_mfma_f32_16x16x32_bf16(Al, Bh, C[b], 0, 0, 0);
            C[b] = __builtin_amdgcn_mfma_f32_16x16x32_bf16(Ah, Bl, C[b], 0, 0, 0);
        }
    }

    float s[4] = { 0.f, 0.f, 0.f, 0.f };
#pragma unroll
    for (int r = 0; r < 4; ++r) {
        float* orow = outp + (size_t)(m0 + (grp << 2) + r) * DD + ncol;
#pragma unroll
        for (int b = 0; b < 8; ++b) {
            const float a = C[b][r] + im[r] * wgi[b];
            const float g = 1.0f / (1.0f + expf(-a));
            const float o = fmaf(g, cvD[b][r] - xvD[b][r], xvD[b][r]);
            orow[b * 16] = o;
            s[r] += o * wp8[b];
        }
    }
#pragma unroll
    for (int off = 1; off < 16; off <<= 1) {
        s[0] += __shfl_xor(s[0], off, 64);
        s[1] += __shfl_xor(s[1], off, 64);
        s[2] += __shfl_xor(s[2], off, 64);
        s[3] += __shfl_xor(s[3], off, 64);
    }
    if (ncol < 4) {
        const float v = (ncol == 0) ? s[0] : (ncol == 1) ? s[1] : (ncol == 2) ? s[2] : s[3];
        prop[m0 + (grp << 2) + ncol] = v + bps;
    }
}

extern "C" void kernel_launch(void* const* d_in, const int* in_sizes, int n_in,
                              void* d_out, int out_size, void* d_ws, size_t ws_size,
                              hipStream_t stream) {
    const float* x   = (const float*)d_in[0];
    const int*   ei  = (const int*)d_in[1];
    const float* ea  = (const float*)d_in[2];
    const float* imp = (const float*)d_in[3];
    const float* We  = (const float*)d_in[4];
    const float* be  = (const float*)d_in[5];
    const float* Wc  = (const float*)d_in[6];
    const float* bc  = (const float*)d_in[7];
    const float* Wg  = (const float*)d_in[8];
    const float* bg  = (const float*)d_in[9];
    const float* Wp  = (const float*)d_in[10];
    const float* bp  = (const float*)d_in[11];

    float* out  = (float*)d_out;                 // [NN, DD]
    float* prop = out + (size_t)NN * DD;         // [NN]

    // ws layout
    float* pre    = (float*)d_ws;                               // NN*DD f32
    int*   bsum   = (int*)d_ws;                                 // NB (dead before k_agg)
    int*   bexcl  = (int*)((char*)d_ws + 4096);                 // NB (dead before k_agg)
    int*   counts = (int*)((char*)d_ws + 25600000);             // NN
    int*   rowptr = (int*)((char*)d_ws + 25800000);             // NN+1
    int*   cursor = (int*)((char*)d_ws + 26000064);             // NN
    int2*  sdat   = (int2*)((char*)d_ws + 26200192);            // NE int2

    hipMemsetAsync(counts, 0, NN * sizeof(int), stream);
    hipLaunchKernelGGL(k_hist,    dim3(2048), dim3(256), 0, stream, ei, counts);
    hipLaunchKernelGGL(k_bsum,    dim3(NB),   dim3(256), 0, stream, counts, bsum);
    hipLaunchKernelGGL(k_scanb,   dim3(1),    dim3(256), 0, stream, bsum, bexcl);
    hipLaunchKernelGGL(k_rowptr,  dim3(NB),   dim3(256), 0, stream, counts, bexcl, rowptr, cursor);
    hipLaunchKernelGGL(k_scatter, dim3(2048), dim3(256), 0, stream, ei, cursor, sdat);
    hipLaunchKernelGGL(k_agg,     dim3(6250), dim3(256), 0, stream,
                       x, ea, We, be, rowptr, sdat, pre);
    hipLaunchKernelGGL(k_conv,    dim3(782),  dim3(256), 0, stream, pre, Wc, bc, out);
    hipLaunchKernelGGL(k_gate,    dim3(782),  dim3(256), 0, stream,
                       x, out, imp, Wg, bg, Wp, bp, out, prop);
}